// Round 7
// baseline (276.112 us; speedup 1.0000x reference)
//
#include <hip/hip_runtime.h>
#include <math.h>

// CapsuleLayer round 7: 3 blocks/CU (75% occupancy target).
// r6 was occupancy-capped (64-AGPR acc -> 4 waves/SIMD; 74KB LDS -> 2 blk).
// Fix: wave tile 4mt x 2nf (acc 32 regs), launch_bounds(512,6) -> 85 regs,
// LDS 45.4KB via column-half producer/consumer interleave (A->B, C->D) and
// a single 37KB union region (featA-Khalf / h-half / h2-half / ap).
// Ring-3 register prefetch on W1/CW2 B-loads.

#define BB    1024
#define NN    64
#define FF    512
#define HH    512
#define DD    64
#define VV    16
#define NTT   6
#define NOUTT 135

#define TBM     64
#define THREADS 512
#define NBLK    1024

typedef _Float16 f16;
typedef _Float16 f16x8 __attribute__((ext_vector_type(8)));
typedef float f32x4 __attribute__((ext_vector_type(4)));

#define MFMA16(a, b, c) __builtin_amdgcn_mfma_f32_16x16x32_f16((a), (b), (c), 0, 0, 0)

// output offsets (floats), reference return order
#define SZ_VOTE  ((size_t)BB*NN*VV*9)
#define OFF_VOTE  ((size_t)0)
#define OFF_SCALE (SZ_VOTE)
#define OFF_PRES  (OFF_SCALE + (size_t)BB*NN*VV)
#define OFF_PLC   (OFF_PRES  + (size_t)BB*NN*VV)
#define OFF_PLV   (OFF_PLC   + (size_t)BB*NN)
#define OFF_LOSS  (OFF_PLV   + (size_t)BB*NN*VV)
#define OFF_RAW   (OFF_LOSS  + 1)

// ws layout (bytes)
#define WS_LOSSP 0
#define WS_W1H   ((size_t)8192)
#define WS_W2H   (WS_W1H  + 33554432)   // 64*512*512*2
#define WS_CW1H  (WS_W2H  + 4194304)    // 64*512*64*2
#define WS_CW2H  (WS_CW1H + 4194304)    // 64*64*512*2
#define WS_NEED  (WS_CW2H + 9437184)    // 64*512*144*2

__device__ __forceinline__ float sigmoidf_(float x) { return 1.f / (1.f + expf(-x)); }
__device__ __forceinline__ float softplusf_(float x) { return (x > 20.f) ? x : log1pf(expf(x)); }

__device__ __forceinline__ void make_tr(const float* p, float* M) {
  float scale = sigmoidf_(p[0]) + 1e-2f;
  float tx = tanhf(p[4] * 5.f);
  float ty = tanhf(p[5] * 5.f);
  float th = p[2] * 6.28318530717958647692f;
  float c = cosf(th), s = sinf(th);
  M[0] = scale * c; M[1] = -scale * s; M[2] = tx;
  M[3] = scale * s; M[4] =  scale * c; M[5] = ty;
  M[6] = 0.f;       M[7] = 0.f;        M[8] = 1.f;
}

// ---------------- prepass: fp32 [64][K][Nsz] -> frag-major fp16 ----------------
__global__ void conv_fragB(const float* __restrict__ src, f16* __restrict__ dst,
                           int capStride, int Nsz, int Kc, int Nf) {
  const int tid = blockIdx.x * 256 + threadIdx.x;
  const int total = 64 * Kc * Nf * 64;
  if (tid >= total) return;
  const int c = tid & 15, g = (tid >> 4) & 3;
  int q = tid >> 6;
  const int nf = q % Nf; q /= Nf;
  const int kc = q % Kc; const int n = q / Kc;
  const int col = nf * 16 + c;
  const float* s = src + (size_t)n * capStride + (size_t)(kc * 32 + g * 8) * Nsz + col;
  f16x8 v;
  #pragma unroll
  for (int j = 0; j < 8; ++j) {
    float x = (col < Nsz) ? s[(size_t)j * Nsz] : 0.f;
    v[j] = (f16)x;
  }
  *(f16x8*)(dst + (size_t)tid * 8) = v;
}

// ---------------- main MFMA kernel ----------------
__global__ __launch_bounds__(THREADS, 6)
void caps_mfma(const float* __restrict__ feature,
               const float* __restrict__ mlp_b1,
               const float* __restrict__ mlp_b2,
               const float* __restrict__ caps_w1,     // ones-row (row 64) fp32
               const f16*  __restrict__ w1h,
               const f16*  __restrict__ w2h,
               const f16*  __restrict__ cw1h,
               const f16*  __restrict__ cw2h,
               const float* __restrict__ bias_cvr,
               const float* __restrict__ bias_pl_caps,
               const float* __restrict__ bias_pl_vote,
               const float* __restrict__ bias_scale,
               const float* __restrict__ cpr_static,
               float* __restrict__ out,
               float* __restrict__ lossp)
{
  // 37120B union region: featA K-half / h-half / h2-half (f16, 32KB used)
  // OR ap f32[64][145] (37120B). + raw 8KB. Total 45.4KB -> 3 blocks/CU.
  __shared__ __align__(16) float RbigF[9280];
  __shared__ __align__(16) f16 Rraw[4096];
  __shared__ float red[8];
  f16* RB = (f16*)RbigF;

  const int t   = threadIdx.x;
  const int w   = t >> 6;      // 0..7
  const int ln  = t & 63;
  const int g   = ln >> 4;
  const int c16 = ln & 15;

  const int bid = blockIdx.x;
  const int xcd = bid & 7;
  const int j_  = bid >> 3;
  const int n   = (xcd << 3) + (j_ >> 4);
  const int b0  = (j_ & 15) * TBM;

  const int dnf = w & 3, mh = w >> 2;   // phase-B role

  // =============== Phase A+B interleaved over column halves ===============
  f32x4 accB[2];
  accB[0] = (f32x4)0.f; accB[1] = (f32x4)0.f;

  for (int cp = 0; cp < 2; ++cp) {
    f32x4 acc[4][2];
    #pragma unroll
    for (int mt = 0; mt < 4; ++mt) { acc[mt][0] = (f32x4)0.f; acc[mt][1] = (f32x4)0.f; }

    for (int kh = 0; kh < 2; ++kh) {
      // ---- stage featA K-half: koct_global = kh*32 + koctl, layout [mt4][koctl32][c16][j8]
      #pragma unroll
      for (int rr4 = 0; rr4 < 4; ++rr4) {
        const int rr = rr4 * 8 + w;
        const int mt = rr >> 3, kb = (rr & 7) * 4;
        const int koctl = kb + g;
        const int brow = b0 + mt * 16 + c16;
        const float* fp = feature + ((size_t)brow * NN + n) * FF + (size_t)(kh * 32 + koctl) * 8;
        const float4 f0 = *(const float4*)fp;
        const float4 f1 = *(const float4*)(fp + 4);
        f16x8 v;
        v[0]=(f16)f0.x; v[1]=(f16)f0.y; v[2]=(f16)f0.z; v[3]=(f16)f0.w;
        v[4]=(f16)f1.x; v[5]=(f16)f1.y; v[6]=(f16)f1.z; v[7]=(f16)f1.w;
        *(f16x8*)(RB + mt * 4096 + koctl * 128 + c16 * 8) = v;
      }
      __syncthreads();

      // ---- compute 8 kc of this K-half; wave cols nf = cp*16 + 2w + {0,1}
      const f16* wp = w1h + (size_t)n * 262144 + (size_t)(cp * 16 + 2 * w) * 512 + (size_t)ln * 8;
      f16x8 bb[3][2];
      #pragma unroll
      for (int d = 0; d < 2; ++d) {
        bb[0][d] = *(const f16x8*)(wp + (size_t)(kh * 8 + 0) * 16384 + (size_t)d * 512);
        bb[1][d] = *(const f16x8*)(wp + (size_t)(kh * 8 + 1) * 16384 + (size_t)d * 512);
      }
      #pragma unroll
      for (int kcl = 0; kcl < 8; ++kcl) {
        const int slot = kcl % 3;
        f16x8 af[4];
        #pragma unroll
        for (int mt = 0; mt < 4; ++mt)
          af[mt] = *(const f16x8*)(RB + mt * 4096 + (kcl * 4 + g) * 128 + c16 * 8);
        #pragma unroll
        for (int d = 0; d < 2; ++d)
          #pragma unroll
          for (int mt = 0; mt < 4; ++mt)
            acc[mt][d] = MFMA16(af[mt], bb[slot][d], acc[mt][d]);
        if (kcl + 2 < 8) {
          const int s2 = (kcl + 2) % 3;
          #pragma unroll
          for (int d = 0; d < 2; ++d)
            bb[s2][d] = *(const f16x8*)(wp + (size_t)(kh * 8 + kcl + 2) * 16384 + (size_t)d * 512);
        }
      }
      __syncthreads();   // all featA reads done; region reusable
    }

    // ---- preload W2 B-frags for this K-half of phase B (issue early) ----
    f16x8 bw[8];
    {
      const f16* w2p = w2h + (size_t)n * 32768 + (size_t)dnf * 512 + (size_t)ln * 8;
      #pragma unroll
      for (int kcl = 0; kcl < 8; ++kcl)
        bw[kcl] = *(const f16x8*)(w2p + (size_t)(cp * 8 + kcl) * 2048);
    }

    // ---- write h-half (bias+relu) into RB, frag-major over local K-half ----
    {
      const float* b1n = mlp_b1 + (size_t)n * HH;
      #pragma unroll
      for (int d = 0; d < 2; ++d) {
        const int hcol = cp * 256 + w * 32 + d * 16 + c16;
        const float bbv = b1n[hcol];
        const int lc = w * 32 + d * 16 + c16;
        const int koctl = lc >> 3, jj = lc & 7;
        #pragma unroll
        for (int mt = 0; mt < 4; ++mt)
          #pragma unroll
          for (int r = 0; r < 4; ++r)
            RB[mt * 4096 + koctl * 128 + (g * 4 + r) * 8 + jj] =
                (f16)fmaxf(acc[mt][d][r] + bbv, 0.f);
      }
    }
    __syncthreads();   // h-half visible

    // ---- phase B partial: accB += h_half @ W2_half ----
    #pragma unroll
    for (int kcl = 0; kcl < 8; ++kcl) {
      const f16x8 a0 = *(const f16x8*)(RB + (2 * mh)     * 4096 + (kcl * 4 + g) * 128 + c16 * 8);
      const f16x8 a1 = *(const f16x8*)(RB + (2 * mh + 1) * 4096 + (kcl * 4 + g) * 128 + c16 * 8);
      accB[0] = MFMA16(a0, bw[kcl], accB[0]);
      accB[1] = MFMA16(a1, bw[kcl], accB[1]);
    }
    __syncthreads();   // h-half reads done; region free for next cp
  }

  // ---- raw = accB + b2 -> out + Rraw ----
  {
    const int dcol = dnf * 16 + c16;
    const float bb2 = mlp_b2[(size_t)n * DD + dcol];
    const int koct = dcol >> 3, jj = dcol & 7;
    #pragma unroll
    for (int i = 0; i < 2; ++i) {
      const int mt = 2 * mh + i;
      const f32x4 a = i ? accB[1] : accB[0];
      #pragma unroll
      for (int r = 0; r < 4; ++r) {
        const int m = mt * 16 + g * 4 + r;
        const float v = a[r] + bb2;
        out[OFF_RAW + (((size_t)(b0 + m)) * NN + n) * DD + dcol] = v;
        Rraw[mt * 1024 + koct * 128 + (g * 4 + r) * 8 + jj] = (f16)v;
      }
    }
  }
  __syncthreads();   // raw visible; RB free

  // =============== Phase C+D interleaved over column halves ===============
  f32x4 accD[4], accD8[4];
  #pragma unroll
  for (int mt = 0; mt < 4; ++mt) { accD[mt] = (f32x4)0.f; accD8[mt] = (f32x4)0.f; }
  const bool w0 = (w == 0);

  for (int cp = 0; cp < 2; ++cp) {
    // ---- phase C partial: h2-half = relu(raw @ CW1 + ones-row), cols cp*256.. ----
    f32x4 accC[4][2];
    #pragma unroll
    for (int mt = 0; mt < 4; ++mt) { accC[mt][0] = (f32x4)0.f; accC[mt][1] = (f32x4)0.f; }
    {
      const f16* cw1p = cw1h + (size_t)n * 32768 + (size_t)(cp * 16 + 2 * w) * 512 + (size_t)ln * 8;
      f16x8 bc[2][2];
      #pragma unroll
      for (int kc = 0; kc < 2; ++kc)
        #pragma unroll
        for (int d = 0; d < 2; ++d)
          bc[kc][d] = *(const f16x8*)(cw1p + (size_t)kc * 16384 + (size_t)d * 512);
      #pragma unroll
      for (int kc = 0; kc < 2; ++kc) {
        f16x8 af[4];
        #pragma unroll
        for (int mt = 0; mt < 4; ++mt)
          af[mt] = *(const f16x8*)(Rraw + mt * 1024 + (kc * 4 + g) * 128 + c16 * 8);
        #pragma unroll
        for (int d = 0; d < 2; ++d)
          #pragma unroll
          for (int mt = 0; mt < 4; ++mt)
            accC[mt][d] = MFMA16(af[mt], bc[kc][d], accC[mt][d]);
      }
    }
    {
      const float* cl = caps_w1 + ((size_t)n * 65 + 64) * HH;
      #pragma unroll
      for (int d = 0; d < 2; ++d) {
        const int hcol = cp * 256 + w * 32 + d * 16 + c16;
        const float ev = cl[hcol];
        const int lc = w * 32 + d * 16 + c16;
        const int koctl = lc >> 3, jj = lc & 7;
        #pragma unroll
        for (int mt = 0; mt < 4; ++mt)
          #pragma unroll
          for (int r = 0; r < 4; ++r)
            RB[mt * 4096 + koctl * 128 + (g * 4 + r) * 8 + jj] =
                (f16)fmaxf(accC[mt][d][r] + ev, 0.f);
      }
    }
    __syncthreads();   // h2-half visible

    // ---- phase D partial: accD += h2_half @ CW2_half; wave nf=w (+8 for w0) ----
    {
      const f16* cw2p = cw2h + (size_t)n * 73728 + (size_t)ln * 8;
      f16x8 db[3], db8[3];
      db[0] = *(const f16x8*)(cw2p + (size_t)(cp * 8 + 0) * 4608 + (size_t)w * 512);
      db[1] = *(const f16x8*)(cw2p + (size_t)(cp * 8 + 1) * 4608 + (size_t)w * 512);
      if (w0) {
        db8[0] = *(const f16x8*)(cw2p + (size_t)(cp * 8 + 0) * 4608 + (size_t)8 * 512);
        db8[1] = *(const f16x8*)(cw2p + (size_t)(cp * 8 + 1) * 4608 + (size_t)8 * 512);
      }
      #pragma unroll
      for (int kcl = 0; kcl < 8; ++kcl) {
        const int slot = kcl % 3;
        f16x8 af[4];
        #pragma unroll
        for (int mt = 0; mt < 4; ++mt)
          af[mt] = *(const f16x8*)(RB + mt * 4096 + (kcl * 4 + g) * 128 + c16 * 8);
        #pragma unroll
        for (int mt = 0; mt < 4; ++mt) accD[mt] = MFMA16(af[mt], db[slot], accD[mt]);
        if (w0) {
          #pragma unroll
          for (int mt = 0; mt < 4; ++mt) accD8[mt] = MFMA16(af[mt], db8[slot], accD8[mt]);
        }
        if (kcl + 2 < 8) {
          const int s2 = (kcl + 2) % 3;
          db[s2] = *(const f16x8*)(cw2p + (size_t)(cp * 8 + kcl + 2) * 4608 + (size_t)w * 512);
          if (w0)
            db8[s2] = *(const f16x8*)(cw2p + (size_t)(cp * 8 + kcl + 2) * 4608 + (size_t)8 * 512);
        }
      }
    }
    __syncthreads();   // D reads done; RB free for next cp / ap
  }

  // ---- stage all_param f32 into RbigF as ap[64][145] ----
  float* apf = RbigF;
  {
    const int col = w * 16 + c16;
    #pragma unroll
    for (int mt = 0; mt < 4; ++mt)
      #pragma unroll
      for (int r = 0; r < 4; ++r)
        apf[(size_t)(mt * 16 + g * 4 + r) * 145 + col] = accD[mt][r];
    if (w0) {
      const int col8 = 128 + c16;
      if (col8 < NOUTT) {
        #pragma unroll
        for (int mt = 0; mt < 4; ++mt)
          #pragma unroll
          for (int r = 0; r < 4; ++r)
            apf[(size_t)(mt * 16 + g * 4 + r) * 145 + col8] = accD8[mt][r];
      }
    }
  }
  __syncthreads();

  // ---- loss partial: sum ap[:,0:96]^2 over 64 rows ----
  {
    const int mrow = t >> 3, seg = t & 7;
    const float* ar = apf + (size_t)mrow * 145 + seg * 12;
    float ls = 0.f;
    #pragma unroll
    for (int i = 0; i < 12; ++i) ls += ar[i] * ar[i];
    ls += __shfl_down(ls, 32); ls += __shfl_down(ls, 16); ls += __shfl_down(ls, 8);
    ls += __shfl_down(ls, 4);  ls += __shfl_down(ls, 2);  ls += __shfl_down(ls, 1);
    if (ln == 0) red[w] = ls;
    __syncthreads();
    if (t == 0) {
      float s = 0.f;
      #pragma unroll
      for (int i = 0; i < 8; ++i) s += red[i];
      lossp[bid] = s;
    }
  }

  // ---- epilogue transforms (64 rows x 16 votes) ----
  for (int vt = t; vt < TBM * VV; vt += THREADS) {
    const int m = vt >> 4;
    const int v = vt & 15;
    const float* aprow = apf + (size_t)m * 145;
    float pd[6], pc[6];
    #pragma unroll
    for (int ii = 0; ii < 6; ++ii)
      pd[ii] = aprow[v * NTT + ii] + cpr_static[((size_t)n * VV + v) * NTT + ii];
    #pragma unroll
    for (int ii = 0; ii < 6; ++ii)
      pc[ii] = aprow[96 + ii] + bias_cvr[(size_t)n * NTT + ii];
    float Ma[9], Mb[9], Mv[9];
    make_tr(pc, Ma);
    make_tr(pd, Mb);
    #pragma unroll
    for (int r = 0; r < 3; ++r)
      #pragma unroll
      for (int c = 0; c < 3; ++c)
        Mv[r * 3 + c] = Ma[r*3+0] * Mb[0*3+c] + Ma[r*3+1] * Mb[1*3+c] + Ma[r*3+2] * Mb[2*3+c];
    const int b = b0 + m;
    const size_t vbase = (((size_t)b * NN + n) * VV + v) * 9;
    #pragma unroll
    for (int k = 0; k < 9; ++k) out[OFF_VOTE + vbase + k] = Mv[k];
    const size_t sidx = ((size_t)b * NN + n) * VV + v;
    out[OFF_SCALE + sidx] = softplusf_(aprow[119 + v] + bias_scale[(size_t)n * VV + v] + 0.5f) + 0.01f;
    const float plv = aprow[103 + v] + bias_pl_vote[(size_t)n * VV + v];
    out[OFF_PLV + sidx] = plv;
    const float plc = aprow[102] + bias_pl_caps[n];
    if (v == 0) out[OFF_PLC + (size_t)b * NN + n] = plc;
    out[OFF_PRES + sidx] = sigmoidf_(plc) * sigmoidf_(plv);
  }
}

// ---------------- fp32 fallback (round-2 kernel, TBM=32, 2048 blocks) ----------------
struct SA  { float featT[16][36]; float w1c[16][512]; };
struct SBp { float hbuf[32][128]; float w2c[128][64]; };
struct SC  { float cpT[64][32];  float cw1c[16][512]; };
struct SD  { float h2buf[32][68]; float cw2c[64][168]; };
struct SP  { float ap[32][136]; };
union  SH  { SA a; SBp b; SC c; SD d; SP p; };

__global__ __launch_bounds__(256)
void caps_fp32(const float* __restrict__ feature, const float* __restrict__ mlp_w1,
               const float* __restrict__ mlp_b1, const float* __restrict__ mlp_w2,
               const float* __restrict__ mlp_b2, const float* __restrict__ caps_w1,
               const float* __restrict__ caps_w2, const float* __restrict__ bias_cvr,
               const float* __restrict__ bias_pl_caps, const float* __restrict__ bias_pl_vote,
               const float* __restrict__ bias_scale, const float* __restrict__ cpr_static,
               float* __restrict__ out, float* __restrict__ lossp)
{
  __shared__ SH sh;
  __shared__ float red4[4];
  const int t  = threadIdx.x;
  const int wv = t >> 6;
  const int ln = t & 63;
  const int m0 = wv << 3;
  const int cA0 = ln << 2;
  const int cA1 = 256 + (ln << 2);
  const int bid   = blockIdx.x;
  const int xcd   = bid & 7;
  const int j     = bid >> 3;
  const int n     = (xcd << 3) + (j >> 5);
  const int mtile = j & 31;
  const int b0    = mtile * 32;

  float acc[64];
  #pragma unroll
  for (int i = 0; i < 64; ++i) acc[i] = 0.f;
  {
    const float* w1n = mlp_w1 + (size_t)n * FF * HH;
    for (int k0 = 0; k0 < FF; k0 += 16) {
      for (int e = t; e < 512; e += 256) {
        const int mm = e >> 4, kk = e & 15;
        sh.a.featT[kk][mm] = feature[(((size_t)(b0 + mm)) * NN + n) * FF + (k0 + kk)];
      }
      { const float4* src = (const float4*)(w1n + (size_t)k0 * HH);
        float4* dst = (float4*)sh.a.w1c;
        for (int u = t; u < 2048; u += 256) dst[u] = src[u]; }
      __syncthreads();
      #pragma unroll 4
      for (int kk = 0; kk < 16; ++kk) {
        const float4 a0  = *(const float4*)&sh.a.featT[kk][m0];
        const float4 a1  = *(const float4*)&sh.a.featT[kk][m0 + 4];
        const float4 bv0 = *(const float4*)&sh.a.w1c[kk][cA0];
        const float4 bv1 = *(const float4*)&sh.a.w1c[kk][cA1];
        const float av[8] = {a0.x, a0.y, a0.z, a0.w, a1.x, a1.y, a1.z, a1.w};
        const float bv[8] = {bv0.x, bv0.y, bv0.z, bv0.w, bv1.x, bv1.y, bv1.z, bv1.w};
        #pragma unroll
        for (int i = 0; i < 8; ++i)
          #pragma unroll
          for (int c = 0; c < 8; ++c) acc[i * 8 + c] += av[i] * bv[c];
      }
      __syncthreads();
    }
    const float* b1n = mlp_b1 + (size_t)n * HH;
    const float4 bb0 = *(const float4*)&b1n[cA0];
    const float4 bb1 = *(const float4*)&b1n[cA1];
    const float bb[8] = {bb0.x, bb0.y, bb0.z, bb0.w, bb1.x, bb1.y, bb1.z, bb1.w};
    #pragma unroll
    for (int i = 0; i < 8; ++i)
      #pragma unroll
      for (int c = 0; c < 8; ++c) acc[i * 8 + c] = fmaxf(acc[i * 8 + c] + bb[c], 0.f);
  }
  float rac[8];
  #pragma unroll
  for (int i = 0; i < 8; ++i) rac[i] = 0.f;
  {
    const float4* w2base = (const float4*)(mlp_w2 + (size_t)n * HH * DD);
    for (int q = 0; q < 4; ++q) {
      if (q == (ln >> 5)) {
        const int lc = (ln & 31) << 2;
        #pragma unroll
        for (int i = 0; i < 8; ++i)
          *(float4*)&sh.b.hbuf[m0 + i][lc] = make_float4(acc[i*8+0], acc[i*8+1], acc[i*8+2], acc[i*8+3]);
      }
      if (q == 2 + (ln >> 5)) {
        const int lc = (ln & 31) << 2;
        #pragma unroll
        for (int i = 0; i < 8; ++i)
          *(float4*)&sh.b.hbuf[m0 + i][lc] = make_float4(acc[i*8+4], acc[i*8+5], acc[i*8+6], acc[i*8+7]);
      }
      { const float4* src = w2base + (size_t)q * 2048;
        float4* dst = (float4*)sh.b.w2c;
        for (int u = t; u < 2048; u += 256) dst[u] = src[u]; }
      __syncthreads();
      #pragma unroll 2
      for (int kk = 0; kk < 128; kk += 4) {
        const float w0  = sh.b.w2c[kk + 0][ln];
        const float w1_ = sh.b.w2c[kk + 1][ln];
        const float w2_ = sh.b.w2c[kk + 2][ln];
        const float w3_ = sh.b.w2c[kk + 3][ln];
        #pragma unroll
        for (int i = 0; i < 8; ++i) {
          const float4 h4 = *(const float4*)&sh.b.hbuf[m0 + i][kk];
          rac[i] += h4.x * w0 + h4.y * w1_ + h4.z * w2_ + h4.w * w3_;
        }
      }
      __syncthreads();
    }
    const float bb2 = mlp_b2[(size_t)n * DD + ln];
    #pragma unroll
    for (int i = 0; i < 8; ++i) {
      const float rv = rac[i] + bb2;
      out[OFF_RAW + (((size_t)(b0 + m0 + i)) * NN + n) * DD + ln] = rv;
      sh.c.cpT[ln][(m0 + i + ln) & 31] = rv;
    }
  }
  #pragma unroll
  for (int i = 0; i < 64; ++i) acc[i] = 0.f;
  {
    const float* cw1n = caps_w1 + (size_t)n * (DD + 1) * HH;
    for (int k0 = 0; k0 < 64; k0 += 16) {
      const float4* src = (const float4*)(cw1n + (size_t)k0 * HH);
      float4* dst = (float4*)sh.c.cw1c;
      for (int u = t; u < 2048; u += 256) dst[u] = src[u];
      __syncthreads();
      #pragma unroll 4
      for (int kk = 0; kk < 16; ++kk) {
        const int k = k0 + kk;
        float av[8];
        #pragma unroll
        for (int i = 0; i < 8; ++i) av[i] = sh.c.cpT[k][(m0 + i + k) & 31];
        const float4 bv0 = *(const float4*)&sh.c.cw1c[kk][cA0];
        const float4 bv1 = *(const float4*)&sh.c.cw1c[kk][cA1];
        const float bv[8] = {bv0.x, bv0.y, bv0.z, bv0.w, bv1.x, bv1.y, bv1.z, bv1.w};
        #pragma unroll
        for (int i = 0; i < 8; ++i)
          #pragma unroll
          for (int c = 0; c < 8; ++c) acc[i * 8 + c] += av[i] * bv[c];
      }
      __syncthreads();
    }
    const float* cl = cw1n + (size_t)64 * HH;
    const float4 e0 = *(const float4*)&cl[cA0];
    const float4 e1 = *(const float4*)&cl[cA1];
    const float ev[8] = {e0.x, e0.y, e0.z, e0.w, e1.x, e1.y, e1.z, e1.w};
    #pragma unroll
    for (int i = 0; i < 8; ++i)
      #pragma unroll
      for (int c = 0; c < 8; ++c) acc[i * 8 + c] = fmaxf(acc[i * 8 + c] + ev[c], 0.f);
  }
  float ap[17];
  #pragma unroll
  for (int i = 0; i < 17; ++i) ap[i] = 0.f;
  const int mD = t >> 3;
  const int cD = t & 7;
  {
    const float* cw2n = caps_w2 + (size_t)n * HH * NOUTT;
    for (int q = 0; q < 8; ++q) {
      if (q == (ln >> 4)) {
        const int lc = (ln & 15) << 2;
        #pragma unroll
        for (int i = 0; i < 8; ++i)
          *(float4*)&sh.d.h2buf[m0 + i][lc] = make_float4(acc[i*8+0], acc[i*8+1], acc[i*8+2], acc[i*8+3]);
      }
      if (q == 4 + (ln >> 4)) {
        const int lc = (ln & 15) << 2;
        #pragma unroll
        for (int i = 0; i < 8; ++i)
          *(float4*)&sh.d.h2buf[m0 + i][lc] = make_float4(acc[i*8+4], acc[i*8+5], acc[i*8+6], acc[i*8+7]);
      }
      { const float* wsrc = cw2n + (size_t)(q << 6) * NOUTT;
        for (int r = wv; r < 64; r += 4)
          for (int c = ln; c < NOUTT; c += 64)
            sh.d.cw2c[r][c + ((c >> 4) << 2)] = wsrc[(size_t)r * NOUTT + c]; }
      __syncthreads();
      const int base20 = 20 * cD;
      #pragma unroll 2
      for (int kk = 0; kk < 64; ++kk) {
        const float hv = sh.d.h2buf[mD][kk];
        const float4 wa = *(const float4*)&sh.d.cw2c[kk][base20 + 0];
        const float4 wb = *(const float4*)&sh.d.cw2c[kk][base20 + 4];
        const float4 wc = *(const float4*)&sh.d.cw2c[kk][base20 + 8];
        const float4 wd = *(const float4*)&sh.d.cw2c[kk][base20 + 12];
        ap[0]  += hv * wa.x; ap[1]  += hv * wa.y; ap[2]  += hv * wa.z; ap[3]  += hv * wa.w;
        ap[4]  += hv * wb.x; ap[5]  += hv * wb.y; ap[6]  += hv * wb.z; ap[7]  += hv * wb.w;
        ap[8]  += hv * wc.x; ap[9]  += hv * wc.y; ap[10] += hv * wc.z; ap[11] += hv * wc.w;
        ap[12] += hv * wd.x; ap[13] += hv * wd.y; ap[14] += hv * wd.z; ap[15] += hv * wd.w;
        if (cD < 7) ap[16] += hv * sh.d.cw2c[kk][160 + cD];
      }
      __syncthreads();
    }
  }
  #pragma unroll
  for (int i = 0; i < 16; ++i) sh.p.ap[mD][(cD << 4) + i] = ap[i];
  if (cD < 7) sh.p.ap[mD][128 + cD] = ap[16];
  float ls = 0.f;
  if (cD < 6) {
    #pragma unroll
    for (int i = 0; i < 16; ++i) ls += ap[i] * ap[i];
  }
  __syncthreads();
  ls += __shfl_down(ls, 32); ls += __shfl_down(ls, 16); ls += __shfl_down(ls, 8);
  ls += __shfl_down(ls, 4);  ls += __shfl_down(ls, 2);  ls += __shfl_down(ls, 1);
  if (ln == 0) red4[wv] = ls;
  __syncthreads();
  if (t == 0) lossp[bid] = red4[0] + red4[1] + red4[2] + red4[3];
  for (int vt = t; vt < 32 * VV; vt += 256) {
    const int m = vt >> 4;
    const int v = vt & 15;
    const float* aprow = sh.p.ap[m];
    float pd[6], pc[6];
    #pragma unroll
    for (int ii = 0; ii < 6; ++ii)
      pd[ii] = aprow[v * NTT + ii] + cpr_static[((size_t)n * VV + v) * NTT + ii];
    #pragma unroll
    for (int ii = 0; ii < 6; ++ii)
      pc[ii] = aprow[96 + ii] + bias_cvr[(size_t)n * NTT + ii];
    float Ma[9], Mb[9], Mv[9];
    make_tr(pc, Ma);
    make_tr(pd, Mb);
    #pragma unroll
    for (int r = 0; r < 3; ++r)
      #pragma unroll
      for (int c = 0; c < 3; ++c)
        Mv[r * 3 + c] = Ma[r*3+0] * Mb[0*3+c] + Ma[r*3+1] * Mb[1*3+c] + Ma[r*3+2] * Mb[2*3+c];
    const int b = b0 + m;
    const size_t vbase = (((size_t)b * NN + n) * VV + v) * 9;
    #pragma unroll
    for (int k = 0; k < 9; ++k) out[OFF_VOTE + vbase + k] = Mv[k];
    const size_t sidx = ((size_t)b * NN + n) * VV + v;
    out[OFF_SCALE + sidx] = softplusf_(aprow[119 + v] + bias_scale[(size_t)n * VV + v] + 0.5f) + 0.01f;
    const float plv = aprow[103 + v] + bias_pl_vote[(size_t)n * VV + v];
    out[OFF_PLV + sidx] = plv;
    const float plc = aprow[102] + bias_pl_caps[n];
    if (v == 0) out[OFF_PLC + (size_t)b * NN + n] = plc;
    out[OFF_PRES + sidx] = sigmoidf_(plc) * sigmoidf_(plv);
  }
}

__global__ __launch_bounds__(256)
void loss_reduce(const float* __restrict__ lossp, float* __restrict__ out, int nblk) {
  __shared__ float r2[4];
  const int t = threadIdx.x;
  float s = 0.f;
  for (int i = t; i < nblk; i += 256) s += lossp[i];
  s += __shfl_down(s, 32); s += __shfl_down(s, 16); s += __shfl_down(s, 8);
  s += __shfl_down(s, 4);  s += __shfl_down(s, 2);  s += __shfl_down(s, 1);
  if ((t & 63) == 0) r2[t >> 6] = s;
  __syncthreads();
  if (t == 0) out[OFF_LOSS] = (r2[0] + r2[1] + r2[2] + r2[3]) * (0.5f / 1024.f);
}

extern "C" void kernel_launch(void* const* d_in, const int* in_sizes, int n_in,
                              void* d_out, int out_size, void* d_ws, size_t ws_size,
                              hipStream_t stream) {
  (void)in_sizes; (void)n_in; (void)out_size;
  const float* feature      = (const float*)d_in[0];
  const float* mlp_w1       = (const float*)d_in[1];
  const float* mlp_b1       = (const float*)d_in[2];
  const float* mlp_w2       = (const float*)d_in[3];
  const float* mlp_b2       = (const float*)d_in[4];
  const float* caps_w1      = (const float*)d_in[5];
  const float* caps_w2      = (const float*)d_in[6];
  const float* bias_cvr     = (const float*)d_in[7];
  const float* bias_pl_caps = (const float*)d_in[8];
  const float* bias_pl_vote = (const float*)d_in[9];
  const float* bias_scale   = (const float*)d_in[10];
  const float* cpr_static   = (const float*)d_in[11];
  float* out   = (float*)d_out;
  float* lossp = (float*)d_ws;

  if (ws_size >= WS_NEED) {
    f16* w1h  = (f16*)((char*)d_ws + WS_W1H);
    f16* w2h  = (f16*)((char*)d_ws + WS_W2H);
    f16* cw1h = (f16*)((char*)d_ws + WS_CW1H);
    f16* cw2h = (f16*)((char*)d_ws + WS_CW2H);
    hipLaunchKernelGGL(conv_fragB, dim3(2097152 / 256), dim3(256), 0, stream,
                       mlp_w1, w1h, 512 * 512, 512, 16, 32);
    hipLaunchKernelGGL(conv_fragB, dim3(262144 / 256), dim3(256), 0, stream,
                       mlp_w2, w2h, 512 * 64, 64, 16, 4);
    hipLaunchKernelGGL(conv_fragB, dim3(262144 / 256), dim3(256), 0, stream,
                       caps_w1, cw1h, 65 * 512, 512, 2, 32);
    hipLaunchKernelGGL(conv_fragB, dim3(589824 / 256), dim3(256), 0, stream,
                       caps_w2, cw2h, 512 * 135, 135, 16, 9);
    hipLaunchKernelGGL(caps_mfma, dim3(NBLK), dim3(THREADS), 0, stream,
                       feature, mlp_b1, mlp_b2, caps_w1, w1h, w2h, cw1h, cw2h,
                       bias_cvr, bias_pl_caps, bias_pl_vote, bias_scale, cpr_static,
                       out, lossp);
    hipLaunchKernelGGL(loss_reduce, dim3(1), dim3(256), 0, stream, lossp, out, NBLK);
  } else {
    hipLaunchKernelGGL(caps_fp32, dim3(2048), dim3(256), 0, stream,
                       feature, mlp_w1, mlp_b1, mlp_w2, mlp_b2, caps_w1, caps_w2,
                       bias_cvr, bias_pl_caps, bias_pl_vote, bias_scale, cpr_static,
                       out, lossp);
    hipLaunchKernelGGL(loss_reduce, dim3(1), dim3(256), 0, stream, lossp, out, 2048);
  }
}

// Round 9
// 145.268 us; speedup vs baseline: 1.9007x; 1.9007x over previous
//
#include <hip/hip_runtime.h>
#include <math.h>

// CapsuleLayer round 9: r6 (TBM=64, 512 thr, 2 blk/CU) + NON-TEMPORAL streams.
// r8 failed to compile: __builtin_nontemporal_load rejects HIP_vector_type
// (float4); use ext_vector_type(4) float for NT loads.
// Theory (unchanged): feature (128MB) + output (77MB) streams thrash the
// 4MB/XCD L2, evicting W1h between its 16 per-capsule uses -> weight re-reads
// from L3/HBM. NT loads (feature) + NT stores (outputs) keep weights resident.

#define BB    1024
#define NN    64
#define FF    512
#define HH    512
#define DD    64
#define VV    16
#define NTT   6
#define NOUTT 135

#define TBM     64
#define THREADS 512
#define NBLK    1024

typedef _Float16 f16;
typedef _Float16 f16x8 __attribute__((ext_vector_type(8)));
typedef float f32x4 __attribute__((ext_vector_type(4)));

#define MFMA16(a, b, c) __builtin_amdgcn_mfma_f32_16x16x32_f16((a), (b), (c), 0, 0, 0)
#define NTS(v, p)  __builtin_nontemporal_store((v), (p))

// output offsets (floats), reference return order
#define SZ_VOTE  ((size_t)BB*NN*VV*9)
#define OFF_VOTE  ((size_t)0)
#define OFF_SCALE (SZ_VOTE)
#define OFF_PRES  (OFF_SCALE + (size_t)BB*NN*VV)
#define OFF_PLC   (OFF_PRES  + (size_t)BB*NN*VV)
#define OFF_PLV   (OFF_PLC   + (size_t)BB*NN)
#define OFF_LOSS  (OFF_PLV   + (size_t)BB*NN*VV)
#define OFF_RAW   (OFF_LOSS  + 1)

// ws layout (bytes)
#define WS_LOSSP 0
#define WS_W1H   ((size_t)8192)
#define WS_W2H   (WS_W1H  + 33554432)   // 64*512*512*2
#define WS_CW1H  (WS_W2H  + 4194304)    // 64*512*64*2
#define WS_CW2H  (WS_CW1H + 4194304)    // 64*64*512*2
#define WS_NEED  (WS_CW2H + 9437184)    // 64*512*144*2

__device__ __forceinline__ float sigmoidf_(float x) { return 1.f / (1.f + expf(-x)); }
__device__ __forceinline__ float softplusf_(float x) { return (x > 20.f) ? x : log1pf(expf(x)); }

__device__ __forceinline__ void make_tr(const float* p, float* M) {
  float scale = sigmoidf_(p[0]) + 1e-2f;
  float tx = tanhf(p[4] * 5.f);
  float ty = tanhf(p[5] * 5.f);
  float th = p[2] * 6.28318530717958647692f;
  float c = cosf(th), s = sinf(th);
  M[0] = scale * c; M[1] = -scale * s; M[2] = tx;
  M[3] = scale * s; M[4] =  scale * c; M[5] = ty;
  M[6] = 0.f;       M[7] = 0.f;        M[8] = 1.f;
}

// ---------------- prepass: fp32 [64][K][Nsz] -> frag-major fp16 ----------------
__global__ void conv_fragB(const float* __restrict__ src, f16* __restrict__ dst,
                           int capStride, int Nsz, int Kc, int Nf) {
  const int tid = blockIdx.x * 256 + threadIdx.x;
  const int total = 64 * Kc * Nf * 64;
  if (tid >= total) return;
  const int c = tid & 15, g = (tid >> 4) & 3;
  int q = tid >> 6;
  const int nf = q % Nf; q /= Nf;
  const int kc = q % Kc; const int n = q / Kc;
  const int col = nf * 16 + c;
  const float* s = src + (size_t)n * capStride + (size_t)(kc * 32 + g * 8) * Nsz + col;
  f16x8 v;
  #pragma unroll
  for (int j = 0; j < 8; ++j) {
    float x = (col < Nsz) ? s[(size_t)j * Nsz] : 0.f;
    v[j] = (f16)x;
  }
  *(f16x8*)(dst + (size_t)tid * 8) = v;
}

// ---------------- main MFMA kernel ----------------
__global__ __launch_bounds__(THREADS, 4)
void caps_mfma(const float* __restrict__ feature,
               const float* __restrict__ mlp_b1,
               const float* __restrict__ mlp_b2,
               const float* __restrict__ caps_w1,     // ones-row (row 64) fp32
               const f16*  __restrict__ w1h,
               const f16*  __restrict__ w2h,
               const f16*  __restrict__ cw1h,
               const f16*  __restrict__ cw2h,
               const float* __restrict__ bias_cvr,
               const float* __restrict__ bias_pl_caps,
               const float* __restrict__ bias_pl_vote,
               const float* __restrict__ bias_scale,
               const float* __restrict__ cpr_static,
               float* __restrict__ out,
               float* __restrict__ lossp)
{
  __shared__ __align__(16) f16 R0h[32768];   // 64KB: featA -> h -> h2 -> ap(f32)
  __shared__ __align__(16) f16 Rraw[4096];   // 8KB raw frag-major (4 mt)
  __shared__ float red[8];

  const int t   = threadIdx.x;
  const int w   = t >> 6;      // 0..7
  const int ln  = t & 63;
  const int g   = ln >> 4;     // k-group within fragment
  const int c16 = ln & 15;     // row (A) / col (B) index within fragment

  const int bid = blockIdx.x;
  const int xcd = bid & 7;
  const int j_  = bid >> 3;           // 0..127
  const int n   = (xcd << 3) + (j_ >> 4);
  const int b0  = (j_ & 15) * TBM;

  // ---- stage feature -> R0 frag-major fp16 (NT: stream, don't pollute L2) ----
  for (int rr = w; rr < 64; rr += 8) {
    const int mt = rr >> 4, kb = (rr & 15) * 4;
    const int koct = kb + g;
    const int brow = b0 + mt * 16 + c16;
    const float* fp = feature + ((size_t)brow * NN + n) * FF + koct * 8;
    const f32x4 f0 = __builtin_nontemporal_load((const f32x4*)fp);
    const f32x4 f1 = __builtin_nontemporal_load((const f32x4*)(fp + 4));
    f16x8 v;
    v[0]=(f16)f0.x; v[1]=(f16)f0.y; v[2]=(f16)f0.z; v[3]=(f16)f0.w;
    v[4]=(f16)f1.x; v[5]=(f16)f1.y; v[6]=(f16)f1.z; v[7]=(f16)f1.w;
    *(f16x8*)(R0h + mt * 8192 + koct * 128 + c16 * 8) = v;
  }
  __syncthreads();

  // ---- Phase A: h = relu(feat @ W1 + b1); wave w owns cols [64w,64w+64) ----
  f32x4 acc[4][4];   // [mt][nf] = 64 AGPR
  #pragma unroll
  for (int mt = 0; mt < 4; ++mt)
    #pragma unroll
    for (int nf = 0; nf < 4; ++nf) acc[mt][nf] = (f32x4)0.f;

  {
    const f16* wp = w1h + (size_t)n * 16 * 16384 + (size_t)(w * 4) * 512 + (size_t)ln * 8;
    f16x8 bA[4], bB[4];
    #pragma unroll
    for (int nf = 0; nf < 4; ++nf) bA[nf] = *(const f16x8*)(wp + (size_t)nf * 512);
    #pragma unroll
    for (int kc = 0; kc < 16; kc += 2) {
      #pragma unroll
      for (int nf = 0; nf < 4; ++nf)
        bB[nf] = *(const f16x8*)(wp + (size_t)(kc + 1) * 16384 + (size_t)nf * 512);
      f16x8 af[4];
      #pragma unroll
      for (int mt = 0; mt < 4; ++mt)
        af[mt] = *(const f16x8*)(R0h + mt * 8192 + (kc * 4 + g) * 128 + c16 * 8);
      #pragma unroll
      for (int nf = 0; nf < 4; ++nf)
        #pragma unroll
        for (int mt = 0; mt < 4; ++mt)
          acc[mt][nf] = MFMA16(af[mt], bA[nf], acc[mt][nf]);
      if (kc + 2 < 16) {
        #pragma unroll
        for (int nf = 0; nf < 4; ++nf)
          bA[nf] = *(const f16x8*)(wp + (size_t)(kc + 2) * 16384 + (size_t)nf * 512);
      }
      #pragma unroll
      for (int mt = 0; mt < 4; ++mt)
        af[mt] = *(const f16x8*)(R0h + mt * 8192 + ((kc + 1) * 4 + g) * 128 + c16 * 8);
      #pragma unroll
      for (int nf = 0; nf < 4; ++nf)
        #pragma unroll
        for (int mt = 0; mt < 4; ++mt)
          acc[mt][nf] = MFMA16(af[mt], bB[nf], acc[mt][nf]);
    }
  }
  __syncthreads();   // all featA reads done

  // ---- write h (bias+relu) into R0h ----
  {
    const float* b1n = mlp_b1 + (size_t)n * HH;
    #pragma unroll
    for (int nf = 0; nf < 4; ++nf) {
      const int hcol = w * 64 + nf * 16 + c16;
      const float bb = b1n[hcol];
      const int koct = hcol >> 3, jj = hcol & 7;
      #pragma unroll
      for (int mt = 0; mt < 4; ++mt)
        #pragma unroll
        for (int r = 0; r < 4; ++r)
          R0h[mt * 8192 + koct * 128 + (g * 4 + r) * 8 + jj] =
              (f16)fmaxf(acc[mt][nf][r] + bb, 0.f);
    }
  }
  __syncthreads();   // h visible

  // ---- Phase B: raw = h @ W2 + b2; wave w: d-cols [16(w&3),+16), mts {2(w>>2),+1} ----
  {
    const int dnf = w & 3, mh = w >> 2;
    f32x4 accB0 = (f32x4)0.f, accB1 = (f32x4)0.f;
    const f16* w2p = w2h + (size_t)n * 16 * 2048 + (size_t)dnf * 512 + (size_t)ln * 8;
    f16x8 bw[16];
    #pragma unroll
    for (int kc = 0; kc < 16; ++kc) bw[kc] = *(const f16x8*)(w2p + (size_t)kc * 2048);
    #pragma unroll
    for (int kc = 0; kc < 16; ++kc) {
      const f16x8 af0 = *(const f16x8*)(R0h + (2 * mh)     * 8192 + (kc * 4 + g) * 128 + c16 * 8);
      const f16x8 af1 = *(const f16x8*)(R0h + (2 * mh + 1) * 8192 + (kc * 4 + g) * 128 + c16 * 8);
      accB0 = MFMA16(af0, bw[kc], accB0);
      accB1 = MFMA16(af1, bw[kc], accB1);
    }
    const int d = dnf * 16 + c16;
    const float bb2 = mlp_b2[(size_t)n * DD + d];
    const int koct = d >> 3, jj = d & 7;
    #pragma unroll
    for (int i = 0; i < 2; ++i) {
      const int mt = 2 * mh + i;
      const f32x4 a = i ? accB1 : accB0;
      #pragma unroll
      for (int r = 0; r < 4; ++r) {
        const int m = mt * 16 + g * 4 + r;
        const float v = a[r] + bb2;
        NTS(v, &out[OFF_RAW + (((size_t)(b0 + m)) * NN + n) * DD + d]);
        Rraw[mt * 1024 + koct * 128 + (g * 4 + r) * 8 + jj] = (f16)v;
      }
    }
  }
  __syncthreads();   // raw visible; h dead

  // ---- Phase C: h2 = relu(raw @ CW1[0:64] + CW1[64]); wave w cols [64w,64w+64) ----
  #pragma unroll
  for (int mt = 0; mt < 4; ++mt)
    #pragma unroll
    for (int nf = 0; nf < 4; ++nf) acc[mt][nf] = (f32x4)0.f;
  {
    const f16* cw1p = cw1h + (size_t)n * 2 * 16384 + (size_t)(w * 4) * 512 + (size_t)ln * 8;
    f16x8 bc0[4], bc1[4];
    #pragma unroll
    for (int nf = 0; nf < 4; ++nf) bc0[nf] = *(const f16x8*)(cw1p + (size_t)nf * 512);
    #pragma unroll
    for (int nf = 0; nf < 4; ++nf) bc1[nf] = *(const f16x8*)(cw1p + 16384 + (size_t)nf * 512);
    #pragma unroll
    for (int kc = 0; kc < 2; ++kc) {
      f16x8 af[4];
      #pragma unroll
      for (int mt = 0; mt < 4; ++mt)
        af[mt] = *(const f16x8*)(Rraw + mt * 1024 + (kc * 4 + g) * 128 + c16 * 8);
      #pragma unroll
      for (int nf = 0; nf < 4; ++nf)
        #pragma unroll
        for (int mt = 0; mt < 4; ++mt)
          acc[mt][nf] = MFMA16(af[mt], kc ? bc1[nf] : bc0[nf], acc[mt][nf]);
    }
    // ones-row bias + relu -> h2 into R0h
    const float* cl = caps_w1 + ((size_t)n * 65 + 64) * HH;
    #pragma unroll
    for (int nf = 0; nf < 4; ++nf) {
      const int hcol = w * 64 + nf * 16 + c16;
      const float ev = cl[hcol];
      const int koct = hcol >> 3, jj = hcol & 7;
      #pragma unroll
      for (int mt = 0; mt < 4; ++mt)
        #pragma unroll
        for (int r = 0; r < 4; ++r)
          R0h[mt * 8192 + koct * 128 + (g * 4 + r) * 8 + jj] =
              (f16)fmaxf(acc[mt][nf][r] + ev, 0.f);
    }
  }
  __syncthreads();   // h2 visible

  // ---- Phase D: ap = h2 @ CW2 (144 cols, 9 nf); wave w: nf=w; wave0 also nf=8 ----
  f32x4 accD[4];
  f32x4 accD8[4];
  #pragma unroll
  for (int mt = 0; mt < 4; ++mt) { accD[mt] = (f32x4)0.f; accD8[mt] = (f32x4)0.f; }
  {
    const f16* cw2p = cw2h + (size_t)n * 16 * 4608 + (size_t)ln * 8;
    const bool w0 = (w == 0);
    f16x8 dA, dB, dA8, dB8;
    dA = *(const f16x8*)(cw2p + (size_t)w * 512);
    if (w0) dA8 = *(const f16x8*)(cw2p + (size_t)8 * 512);
    #pragma unroll
    for (int kc = 0; kc < 16; kc += 2) {
      dB = *(const f16x8*)(cw2p + (size_t)(kc + 1) * 4608 + (size_t)w * 512);
      if (w0) dB8 = *(const f16x8*)(cw2p + (size_t)(kc + 1) * 4608 + (size_t)8 * 512);
      f16x8 af[4];
      #pragma unroll
      for (int mt = 0; mt < 4; ++mt)
        af[mt] = *(const f16x8*)(R0h + mt * 8192 + (kc * 4 + g) * 128 + c16 * 8);
      #pragma unroll
      for (int mt = 0; mt < 4; ++mt) accD[mt] = MFMA16(af[mt], dA, accD[mt]);
      if (w0) {
        #pragma unroll
        for (int mt = 0; mt < 4; ++mt) accD8[mt] = MFMA16(af[mt], dA8, accD8[mt]);
      }
      if (kc + 2 < 16) {
        dA = *(const f16x8*)(cw2p + (size_t)(kc + 2) * 4608 + (size_t)w * 512);
        if (w0) dA8 = *(const f16x8*)(cw2p + (size_t)(kc + 2) * 4608 + (size_t)8 * 512);
      }
      #pragma unroll
      for (int mt = 0; mt < 4; ++mt)
        af[mt] = *(const f16x8*)(R0h + mt * 8192 + ((kc + 1) * 4 + g) * 128 + c16 * 8);
      #pragma unroll
      for (int mt = 0; mt < 4; ++mt) accD[mt] = MFMA16(af[mt], dB, accD[mt]);
      if (w0) {
        #pragma unroll
        for (int mt = 0; mt < 4; ++mt) accD8[mt] = MFMA16(af[mt], dB8, accD8[mt]);
      }
    }
  }
  __syncthreads();   // h2 reads done; R0h free for ap

  // ---- stage all_param f32 into R0 as ap[64][145] ----
  float* apf = (float*)R0h;
  {
    const int col = w * 16 + c16;       // < 128 always
    #pragma unroll
    for (int mt = 0; mt < 4; ++mt)
      #pragma unroll
      for (int r = 0; r < 4; ++r)
        apf[(size_t)(mt * 16 + g * 4 + r) * 145 + col] = accD[mt][r];
    if (w == 0) {
      const int col8 = 128 + c16;
      if (col8 < NOUTT) {
        #pragma unroll
        for (int mt = 0; mt < 4; ++mt)
          #pragma unroll
          for (int r = 0; r < 4; ++r)
            apf[(size_t)(mt * 16 + g * 4 + r) * 145 + col8] = accD8[mt][r];
      }
    }
  }
  __syncthreads();

  // ---- loss partial: sum ap[:,0:96]^2 over 64 rows ----
  {
    const int mrow = t >> 3, seg = t & 7;
    const float* ar = apf + (size_t)mrow * 145 + seg * 12;
    float ls = 0.f;
    #pragma unroll
    for (int i = 0; i < 12; ++i) ls += ar[i] * ar[i];
    ls += __shfl_down(ls, 32); ls += __shfl_down(ls, 16); ls += __shfl_down(ls, 8);
    ls += __shfl_down(ls, 4);  ls += __shfl_down(ls, 2);  ls += __shfl_down(ls, 1);
    if (ln == 0) red[w] = ls;
    __syncthreads();
    if (t == 0) {
      float s = 0.f;
      #pragma unroll
      for (int i = 0; i < 8; ++i) s += red[i];
      lossp[bid] = s;
    }
  }

  // ---- epilogue transforms (64 rows x 16 votes, NT stores) ----
  for (int vt = t; vt < TBM * VV; vt += THREADS) {
    const int m = vt >> 4;
    const int v = vt & 15;
    const float* aprow = apf + (size_t)m * 145;
    float pd[6], pc[6];
    #pragma unroll
    for (int ii = 0; ii < 6; ++ii)
      pd[ii] = aprow[v * NTT + ii] + cpr_static[((size_t)n * VV + v) * NTT + ii];
    #pragma unroll
    for (int ii = 0; ii < 6; ++ii)
      pc[ii] = aprow[96 + ii] + bias_cvr[(size_t)n * NTT + ii];
    float Ma[9], Mb[9], Mv[9];
    make_tr(pc, Ma);
    make_tr(pd, Mb);
    #pragma unroll
    for (int r = 0; r < 3; ++r)
      #pragma unroll
      for (int c = 0; c < 3; ++c)
        Mv[r * 3 + c] = Ma[r*3+0] * Mb[0*3+c] + Ma[r*3+1] * Mb[1*3+c] + Ma[r*3+2] * Mb[2*3+c];
    const int b = b0 + m;
    const size_t vbase = (((size_t)b * NN + n) * VV + v) * 9;
    #pragma unroll
    for (int k = 0; k < 9; ++k) NTS(Mv[k], &out[OFF_VOTE + vbase + k]);
    const size_t sidx = ((size_t)b * NN + n) * VV + v;
    NTS(softplusf_(aprow[119 + v] + bias_scale[(size_t)n * VV + v] + 0.5f) + 0.01f,
        &out[OFF_SCALE + sidx]);
    const float plv = aprow[103 + v] + bias_pl_vote[(size_t)n * VV + v];
    NTS(plv, &out[OFF_PLV + sidx]);
    const float plc = aprow[102] + bias_pl_caps[n];
    if (v == 0) NTS(plc, &out[OFF_PLC + (size_t)b * NN + n]);
    NTS(sigmoidf_(plc) * sigmoidf_(plv), &out[OFF_PRES + sidx]);
  }
}

// ---------------- fp32 fallback (round-2 kernel, TBM=32, 2048 blocks) ----------------
struct SA  { float featT[16][36]; float w1c[16][512]; };
struct SBp { float hbuf[32][128]; float w2c[128][64]; };
struct SC  { float cpT[64][32];  float cw1c[16][512]; };
struct SD  { float h2buf[32][68]; float cw2c[64][168]; };
struct SP  { float ap[32][136]; };
union  SH  { SA a; SBp b; SC c; SD d; SP p; };

__global__ __launch_bounds__(256)
void caps_fp32(const float* __restrict__ feature, const float* __restrict__ mlp_w1,
               const float* __restrict__ mlp_b1, const float* __restrict__ mlp_w2,
               const float* __restrict__ mlp_b2, const float* __restrict__ caps_w1,
               const float* __restrict__ caps_w2, const float* __restrict__ bias_cvr,
               const float* __restrict__ bias_pl_caps, const float* __restrict__ bias_pl_vote,
               const float* __restrict__ bias_scale, const float* __restrict__ cpr_static,
               float* __restrict__ out, float* __restrict__ lossp)
{
  __shared__ SH sh;
  __shared__ float red4[4];
  const int t  = threadIdx.x;
  const int wv = t >> 6;
  const int ln = t & 63;
  const int m0 = wv << 3;
  const int cA0 = ln << 2;
  const int cA1 = 256 + (ln << 2);
  const int bid   = blockIdx.x;
  const int xcd   = bid & 7;
  const int j     = bid >> 3;
  const int n     = (xcd << 3) + (j >> 5);
  const int mtile = j & 31;
  const int b0    = mtile * 32;

  float acc[64];
  #pragma unroll
  for (int i = 0; i < 64; ++i) acc[i] = 0.f;
  {
    const float* w1n = mlp_w1 + (size_t)n * FF * HH;
    for (int k0 = 0; k0 < FF; k0 += 16) {
      for (int e = t; e < 512; e += 256) {
        const int mm = e >> 4, kk = e & 15;
        sh.a.featT[kk][mm] = feature[(((size_t)(b0 + mm)) * NN + n) * FF + (k0 + kk)];
      }
      { const float4* src = (const float4*)(w1n + (size_t)k0 * HH);
        float4* dst = (float4*)sh.a.w1c;
        for (int u = t; u < 2048; u += 256) dst[u] = src[u]; }
      __syncthreads();
      #pragma unroll 4
      for (int kk = 0; kk < 16; ++kk) {
        const float4 a0  = *(const float4*)&sh.a.featT[kk][m0];
        const float4 a1  = *(const float4*)&sh.a.featT[kk][m0 + 4];
        const float4 bv0 = *(const float4*)&sh.a.w1c[kk][cA0];
        const float4 bv1 = *(const float4*)&sh.a.w1c[kk][cA1];
        const float av[8] = {a0.x, a0.y, a0.z, a0.w, a1.x, a1.y, a1.z, a1.w};
        const float bv[8] = {bv0.x, bv0.y, bv0.z, bv0.w, bv1.x, bv1.y, bv1.z, bv1.w};
        #pragma unroll
        for (int i = 0; i < 8; ++i)
          #pragma unroll
          for (int c = 0; c < 8; ++c) acc[i * 8 + c] += av[i] * bv[c];
      }
      __syncthreads();
    }
    const float* b1n = mlp_b1 + (size_t)n * HH;
    const float4 bb0 = *(const float4*)&b1n[cA0];
    const float4 bb1 = *(const float4*)&b1n[cA1];
    const float bb[8] = {bb0.x, bb0.y, bb0.z, bb0.w, bb1.x, bb1.y, bb1.z, bb1.w};
    #pragma unroll
    for (int i = 0; i < 8; ++i)
      #pragma unroll
      for (int c = 0; c < 8; ++c) acc[i * 8 + c] = fmaxf(acc[i * 8 + c] + bb[c], 0.f);
  }
  float rac[8];
  #pragma unroll
  for (int i = 0; i < 8; ++i) rac[i] = 0.f;
  {
    const float4* w2base = (const float4*)(mlp_w2 + (size_t)n * HH * DD);
    for (int q = 0; q < 4; ++q) {
      if (q == (ln >> 5)) {
        const int lc = (ln & 31) << 2;
        #pragma unroll
        for (int i = 0; i < 8; ++i)
          *(float4*)&sh.b.hbuf[m0 + i][lc] = make_float4(acc[i*8+0], acc[i*8+1], acc[i*8+2], acc[i*8+3]);
      }
      if (q == 2 + (ln >> 5)) {
        const int lc = (ln & 31) << 2;
        #pragma unroll
        for (int i = 0; i < 8; ++i)
          *(float4*)&sh.b.hbuf[m0 + i][lc] = make_float4(acc[i*8+4], acc[i*8+5], acc[i*8+6], acc[i*8+7]);
      }
      { const float4* src = w2base + (size_t)q * 2048;
        float4* dst = (float4*)sh.b.w2c;
        for (int u = t; u < 2048; u += 256) dst[u] = src[u]; }
      __syncthreads();
      #pragma unroll 2
      for (int kk = 0; kk < 128; kk += 4) {
        const float w0  = sh.b.w2c[kk + 0][ln];
        const float w1_ = sh.b.w2c[kk + 1][ln];
        const float w2_ = sh.b.w2c[kk + 2][ln];
        const float w3_ = sh.b.w2c[kk + 3][ln];
        #pragma unroll
        for (int i = 0; i < 8; ++i) {
          const float4 h4 = *(const float4*)&sh.b.hbuf[m0 + i][kk];
          rac[i] += h4.x * w0 + h4.y * w1_ + h4.z * w2_ + h4.w * w3_;
        }
      }
      __syncthreads();
    }
    const float bb2 = mlp_b2[(size_t)n * DD + ln];
    #pragma unroll
    for (int i = 0; i < 8; ++i) {
      const float rv = rac[i] + bb2;
      out[OFF_RAW + (((size_t)(b0 + m0 + i)) * NN + n) * DD + ln] = rv;
      sh.c.cpT[ln][(m0 + i + ln) & 31] = rv;
    }
  }
  #pragma unroll
  for (int i = 0; i < 64; ++i) acc[i] = 0.f;
  {
    const float* cw1n = caps_w1 + (size_t)n * (DD + 1) * HH;
    for (int k0 = 0; k0 < 64; k0 += 16) {
      const float4* src = (const float4*)(cw1n + (size_t)k0 * HH);
      float4* dst = (float4*)sh.c.cw1c;
      for (int u = t; u < 2048; u += 256) dst[u] = src[u];
      __syncthreads();
      #pragma unroll 4
      for (int kk = 0; kk < 16; ++kk) {
        const int k = k0 + kk;
        float av[8];
        #pragma unroll
        for (int i = 0; i < 8; ++i) av[i] = sh.c.cpT[k][(m0 + i + k) & 31];
        const float4 bv0 = *(const float4*)&sh.c.cw1c[kk][cA0];
        const float4 bv1 = *(const float4*)&sh.c.cw1c[kk][cA1];
        const float bv[8] = {bv0.x, bv0.y, bv0.z, bv0.w, bv1.x, bv1.y, bv1.z, bv1.w};
        #pragma unroll
        for (int i = 0; i < 8; ++i)
          #pragma unroll
          for (int c = 0; c < 8; ++c) acc[i * 8 + c] += av[i] * bv[c];
      }
      __syncthreads();
    }
    const float* cl = cw1n + (size_t)64 * HH;
    const float4 e0 = *(const float4*)&cl[cA0];
    const float4 e1 = *(const float4*)&cl[cA1];
    const float ev[8] = {e0.x, e0.y, e0.z, e0.w, e1.x, e1.y, e1.z, e1.w};
    #pragma unroll
    for (int i = 0; i < 8; ++i)
      #pragma unroll
      for (int c = 0; c < 8; ++c) acc[i * 8 + c] = fmaxf(acc[i * 8 + c] + ev[c], 0.f);
  }
  float ap[17];
  #pragma unroll
  for (int i = 0; i < 17; ++i) ap[i] = 0.f;
  const int mD = t >> 3;
  const int cD = t & 7;
  {
    const float* cw2n = caps_w2 + (size_t)n * HH * NOUTT;
    for (int q = 0; q < 8; ++q) {
      if (q == (ln >> 4)) {
        const int lc = (ln & 15) << 2;
        #pragma unroll
        for (int i = 0; i < 8; ++i)
          *(float4*)&sh.d.h2buf[m0 + i][lc] = make_float4(acc[i*8+0], acc[i*8+1], acc[i*8+2], acc[i*8+3]);
      }
      if (q == 4 + (ln >> 4)) {
        const int lc = (ln & 15) << 2;
        #pragma unroll
        for (int i = 0; i < 8; ++i)
          *(float4*)&sh.d.h2buf[m0 + i][lc] = make_float4(acc[i*8+4], acc[i*8+5], acc[i*8+6], acc[i*8+7]);
      }
      { const float* wsrc = cw2n + (size_t)(q << 6) * NOUTT;
        for (int r = wv; r < 64; r += 4)
          for (int c = ln; c < NOUTT; c += 64)
            sh.d.cw2c[r][c + ((c >> 4) << 2)] = wsrc[(size_t)r * NOUTT + c]; }
      __syncthreads();
      const int base20 = 20 * cD;
      #pragma unroll 2
      for (int kk = 0; kk < 64; ++kk) {
        const float hv = sh.d.h2buf[mD][kk];
        const float4 wa = *(const float4*)&sh.d.cw2c[kk][base20 + 0];
        const float4 wb = *(const float4*)&sh.d.cw2c[kk][base20 + 4];
        const float4 wc = *(const float4*)&sh.d.cw2c[kk][base20 + 8];
        const float4 wd = *(const float4*)&sh.d.cw2c[kk][base20 + 12];
        ap[0]  += hv * wa.x; ap[1]  += hv * wa.y; ap[2]  += hv * wa.z; ap[3]  += hv * wa.w;
        ap[4]  += hv * wb.x; ap[5]  += hv * wb.y; ap[6]  += hv * wb.z; ap[7]  += hv * wb.w;
        ap[8]  += hv * wc.x; ap[9]  += hv * wc.y; ap[10] += hv * wc.z; ap[11] += hv * wc.w;
        ap[12] += hv * wd.x; ap[13] += hv * wd.y; ap[14] += hv * wd.z; ap[15] += hv * wd.w;
        if (cD < 7) ap[16] += hv * sh.d.cw2c[kk][160 + cD];
      }
      __syncthreads();
    }
  }
  #pragma unroll
  for (int i = 0; i < 16; ++i) sh.p.ap[mD][(cD << 4) + i] = ap[i];
  if (cD < 7) sh.p.ap[mD][128 + cD] = ap[16];
  float ls = 0.f;
  if (cD < 6) {
    #pragma unroll
    for (int i = 0; i < 16; ++i) ls += ap[i] * ap[i];
  }
  __syncthreads();
  ls += __shfl_down(ls, 32); ls += __shfl_down(ls, 16); ls += __shfl_down(ls, 8);
  ls += __shfl_down(ls, 4);  ls += __shfl_down(ls, 2);  ls += __shfl_down(ls, 1);
  if (ln == 0) red4[wv] = ls;
  __syncthreads();
  if (t == 0) lossp[bid] = red4[0] + red4[1] + red4[2] + red4[3];
  for (int vt = t; vt < 32 * VV; vt += 256) {
    const int m = vt >> 4;
    const int v = vt & 15;
    const float* aprow = sh.p.ap[m];
    float pd[6], pc[6];
    #pragma unroll
    for (int ii = 0; ii < 6; ++ii)
      pd[ii] = aprow[v * NTT + ii] + cpr_static[((size_t)n * VV + v) * NTT + ii];
    #pragma unroll
    for (int ii = 0; ii < 6; ++ii)
      pc[ii] = aprow[96 + ii] + bias_cvr[(size_t)n * NTT + ii];
    float Ma[9], Mb[9], Mv[9];
    make_tr(pc, Ma);
    make_tr(pd, Mb);
    #pragma unroll
    for (int r = 0; r < 3; ++r)
      #pragma unroll
      for (int c = 0; c < 3; ++c)
        Mv[r * 3 + c] = Ma[r*3+0] * Mb[0*3+c] + Ma[r*3+1] * Mb[1*3+c] + Ma[r*3+2] * Mb[2*3+c];
    const int b = b0 + m;
    const size_t vbase = (((size_t)b * NN + n) * VV + v) * 9;
    #pragma unroll
    for (int k = 0; k < 9; ++k) out[OFF_VOTE + vbase + k] = Mv[k];
    const size_t sidx = ((size_t)b * NN + n) * VV + v;
    out[OFF_SCALE + sidx] = softplusf_(aprow[119 + v] + bias_scale[(size_t)n * VV + v] + 0.5f) + 0.01f;
    const float plv = aprow[103 + v] + bias_pl_vote[(size_t)n * VV + v];
    out[OFF_PLV + sidx] = plv;
    const float plc = aprow[102] + bias_pl_caps[n];
    if (v == 0) out[OFF_PLC + (size_t)b * NN + n] = plc;
    out[OFF_PRES + sidx] = sigmoidf_(plc) * sigmoidf_(plv);
  }
}

__global__ __launch_bounds__(256)
void loss_reduce(const float* __restrict__ lossp, float* __restrict__ out, int nblk) {
  __shared__ float r2[4];
  const int t = threadIdx.x;
  float s = 0.f;
  for (int i = t; i < nblk; i += 256) s += lossp[i];
  s += __shfl_down(s, 32); s += __shfl_down(s, 16); s += __shfl_down(s, 8);
  s += __shfl_down(s, 4);  s += __shfl_down(s, 2);  s += __shfl_down(s, 1);
  if ((t & 63) == 0) r2[t >> 6] = s;
  __syncthreads();
  if (t == 0) out[OFF_LOSS] = (r2[0] + r2[1] + r2[2] + r2[3]) * (0.5f / 1024.f);
}

extern "C" void kernel_launch(void* const* d_in, const int* in_sizes, int n_in,
                              void* d_out, int out_size, void* d_ws, size_t ws_size,
                              hipStream_t stream) {
  (void)in_sizes; (void)n_in; (void)out_size;
  const float* feature      = (const float*)d_in[0];
  const float* mlp_w1       = (const float*)d_in[1];
  const float* mlp_b1       = (const float*)d_in[2];
  const float* mlp_w2       = (const float*)d_in[3];
  const float* mlp_b2       = (const float*)d_in[4];
  const float* caps_w1      = (const float*)d_in[5];
  const float* caps_w2      = (const float*)d_in[6];
  const float* bias_cvr     = (const float*)d_in[7];
  const float* bias_pl_caps = (const float*)d_in[8];
  const float* bias_pl_vote = (const float*)d_in[9];
  const float* bias_scale   = (const float*)d_in[10];
  const float* cpr_static   = (const float*)d_in[11];
  float* out   = (float*)d_out;
  float* lossp = (float*)d_ws;

  if (ws_size >= WS_NEED) {
    f16* w1h  = (f16*)((char*)d_ws + WS_W1H);
    f16* w2h  = (f16*)((char*)d_ws + WS_W2H);
    f16* cw1h = (f16*)((char*)d_ws + WS_CW1H);
    f16* cw2h = (f16*)((char*)d_ws + WS_CW2H);
    hipLaunchKernelGGL(conv_fragB, dim3(2097152 / 256), dim3(256), 0, stream,
                       mlp_w1, w1h, 512 * 512, 512, 16, 32);
    hipLaunchKernelGGL(conv_fragB, dim3(262144 / 256), dim3(256), 0, stream,
                       mlp_w2, w2h, 512 * 64, 64, 16, 4);
    hipLaunchKernelGGL(conv_fragB, dim3(262144 / 256), dim3(256), 0, stream,
                       caps_w1, cw1h, 65 * 512, 512, 2, 32);
    hipLaunchKernelGGL(conv_fragB, dim3(589824 / 256), dim3(256), 0, stream,
                       caps_w2, cw2h, 512 * 135, 135, 16, 9);
    hipLaunchKernelGGL(caps_mfma, dim3(NBLK), dim3(THREADS), 0, stream,
                       feature, mlp_b1, mlp_b2, caps_w1, w1h, w2h, cw1h, cw2h,
                       bias_cvr, bias_pl_caps, bias_pl_vote, bias_scale, cpr_static,
                       out, lossp);
    hipLaunchKernelGGL(loss_reduce, dim3(1), dim3(256), 0, stream, lossp, out, NBLK);
  } else {
    hipLaunchKernelGGL(caps_fp32, dim3(2048), dim3(256), 0, stream,
                       feature, mlp_w1, mlp_b1, mlp_w2, mlp_b2, caps_w1, caps_w2,
                       bias_cvr, bias_pl_caps, bias_pl_vote, bias_scale, cpr_static,
                       out, lossp);
    hipLaunchKernelGGL(loss_reduce, dim3(1), dim3(256), 0, stream, lossp, out, 2048);
  }
}